// Round 5
// baseline (1256.350 us; speedup 1.0000x reference)
//
#include <hip/hip_runtime.h>
#include <hip/hip_cooperative_groups.h>
#include <math.h>

namespace cg = cooperative_groups;

#define NB 64
#define NP 16320
#define NO 24
#define NC 81
#define TOT (NB * NP)        // 1,044,480 rows
#define NVB (TOT / 1024)     // 1020 virtual blocks of 1024 rows (exact)

// ---------------------------------------------------------------------------
// Workspace layout (bytes):
//   [0,           12288)   best_key  : u64[NB*NO]   (zeroed each launch)
//   [12288,       12544)   npos      : int[NB]      (zeroed)
//   [12544,       12560)   acc       : float[4]     (zeroed) 0=loss_l 1=ce_pos 2=ce_neg
//   [12800,       ...  )   bto       : float[NB*NP]
//   next                   bti       : int  [NB*NP]
//   next                   ce_mine   : float[NB*NP]
// ---------------------------------------------------------------------------

__device__ __forceinline__ float smooth_l1(float d) {
    float a = fabsf(d);
    return (a < 1.0f) ? 0.5f * a * a : a - 0.5f;
}

// 4-float group with alignment 4 (odm_conf rows are 324 B -> only 4-B aligned).
struct f4a { float x, y, z, w; };

// Single fused cooperative kernel: match -> force -> loss -> select -> final.
// Rationale: rounds 0/2/4 proved k_loss's ~450us is invariant to its internal
// structure (phase-staged heavy/light VALU, barrier-free streaming) with all
// pipes <6% busy -- the cost is at the launch level (5 serial dispatches, L2
// flush at each boundary, bto/bti/cem HBM round-trips, 5x cold ramps). One
// kernel with grid.sync() keeps intermediates L2-warm and pays launch/ramp
// costs once. All phases are grid-stride -> correct for any grid size the
// occupancy query picks.
__global__ void k_fused(
    const float* __restrict__ arm_loc, const float* __restrict__ arm_conf,
    const float* __restrict__ odm_loc, const float* __restrict__ odm_conf,
    const float* __restrict__ priors,  const float* __restrict__ gt_boxes,
    const int*   __restrict__ gt_labels,
    unsigned long long* __restrict__ best_key, int* __restrict__ npos,
    float* __restrict__ acc, float* __restrict__ bto, int* __restrict__ bti,
    float* __restrict__ cem, float* __restrict__ out)
{
    cg::grid_group grid = cg::this_grid();
    const int tid  = threadIdx.x;
    const int bidx = blockIdx.x;
    const int gsz  = gridDim.x;
    const int gtid = bidx * 256 + tid;

    // Shared (union of phase needs; ~9.3 KB total)
    __shared__ float        sl[256];
    __shared__ float        sc[256];
    __shared__ unsigned int hist[4][257];
    __shared__ unsigned int scan[256];
    __shared__ unsigned int sh_prefix, sh_mask, sh_krem;
    __shared__ unsigned int scnt[256];

    // ======================= P1: match =======================
    // Each iteration: this block owns 1024 consecutive rows of the flat
    // [B*P] space; each thread owns 4 (c-strided by 256). Waves never
    // straddle a batch (16320 % 64 == 0, all strides multiples of 64).
    for (int vb = bidx; vb < NVB; vb += gsz) {
        const int base = vb * 1024;
        float x0[4], y0[4], x1[4], y1[4], ab[4];
        int   bc[4], pc[4];
        #pragma unroll
        for (int c = 0; c < 4; ++c) {
            const int r = base + c * 256 + tid;
            const int b = r / NP;
            const int p = r - b * NP;
            bc[c] = b; pc[c] = p;
            const float4 l  = ((const float4*)arm_loc)[r];
            const float4 pr = ((const float4*)priors)[p];
            const float cx = pr.x + l.x * 0.1f * pr.z;
            const float cy = pr.y + l.y * 0.1f * pr.w;
            const float wx = pr.z * expf(l.z * 0.2f);
            const float wy = pr.w * expf(l.w * 0.2f);
            x0[c] = cx - wx * 0.5f; y0[c] = cy - wy * 0.5f;
            x1[c] = cx + wx * 0.5f; y1[c] = cy + wy * 0.5f;
            ab[c] = (x1[c] - x0[c]) * (y1[c] - y0[c]);
        }
        float best[4]  = {-1.0f, -1.0f, -1.0f, -1.0f};
        int   besto[4] = {0, 0, 0, 0};

        for (int o = 0; o < NO; ++o) {
            #pragma unroll
            for (int c = 0; c < 4; ++c) {
                const float4 tb = ((const float4*)gt_boxes)[bc[c] * NO + o];
                const float aa = (tb.z - tb.x) * (tb.w - tb.y);
                const float iw = fmaxf(fminf(tb.z, x1[c]) - fmaxf(tb.x, x0[c]), 0.0f);
                const float ih = fmaxf(fminf(tb.w, y1[c]) - fmaxf(tb.y, y0[c]), 0.0f);
                const float inter = iw * ih;
                const float iou = inter / (aa + ab[c] - inter);
                if (iou > best[c]) { best[c] = iou; besto[c] = o; }  // first occurrence
                unsigned long long key =
                    ((unsigned long long)__float_as_uint(iou) << 32)
                    | (unsigned)~(unsigned)pc[c];
                // 64-lane max (batch is wave-uniform per c)
                #pragma unroll
                for (int d = 1; d < 64; d <<= 1) {
                    const unsigned long long k2 = __shfl_xor(key, d, 64);
                    if (k2 > key) key = k2;
                }
                if ((tid & 63) == 0) atomicMax(&best_key[bc[c] * NO + o], key);
            }
        }
        #pragma unroll
        for (int c = 0; c < 4; ++c) {
            const int r = base + c * 256 + tid;
            bto[r] = best[c];
            bti[r] = besto[c];
        }
    }
    __threadfence();
    grid.sync();

    // ======================= P2: force-match =======================
    // One thread per batch; serial o-loop = last-write-wins scatter.
    if (gtid < NB) {
        for (int o = 0; o < NO; ++o) {
            const unsigned long long k = best_key[gtid * NO + o];
            const unsigned p = ~(unsigned)(k & 0xffffffffULL);
            bto[(size_t)gtid * NP + p] = 2.0f;
            bti[(size_t)gtid * NP + p] = o;
        }
    }
    __threadfence();
    grid.sync();

    // ======================= P3: per-row loss =======================
    float local_l = 0.0f, local_ce = 0.0f;
    for (int r = gtid; r < TOT; r += gsz * 256) {
        const size_t row = (size_t)r;
        const int bb = r / NP;
        const int p  = r - bb * NP;

        const float  ov = bto[row];
        const int    ti = bti[row];
        const float2 c  = ((const float2*)arm_conf)[row];

        const float* rowp = odm_conf + row * (size_t)NC;
        const f4a*   rp4  = (const f4a*)rowp;

        float m0, m1, m2, m3, s0, s1, s2, s3;
#define LSE_CHUNK(K0, MC, SC) do {                                             \
        const f4a v0 = rp4[K0 + 0]; const f4a v1 = rp4[K0 + 1];                \
        const f4a v2 = rp4[K0 + 2]; const f4a v3 = rp4[K0 + 3];                \
        const f4a v4 = rp4[K0 + 4];                                            \
        float ax = fmaxf(v0.x, v1.x), ay = fmaxf(v0.y, v1.y);                  \
        float az = fmaxf(v0.z, v1.z), aw = fmaxf(v0.w, v1.w);                  \
        ax = fmaxf(ax, v2.x); ay = fmaxf(ay, v2.y);                            \
        az = fmaxf(az, v2.z); aw = fmaxf(aw, v2.w);                            \
        ax = fmaxf(ax, v3.x); ay = fmaxf(ay, v3.y);                            \
        az = fmaxf(az, v3.z); aw = fmaxf(aw, v3.w);                            \
        ax = fmaxf(ax, v4.x); ay = fmaxf(ay, v4.y);                            \
        az = fmaxf(az, v4.z); aw = fmaxf(aw, v4.w);                            \
        MC = fmaxf(fmaxf(ax, ay), fmaxf(az, aw));                              \
        float ex = __expf(v0.x - MC) + __expf(v1.x - MC) + __expf(v2.x - MC)   \
                 + __expf(v3.x - MC) + __expf(v4.x - MC);                      \
        float ey = __expf(v0.y - MC) + __expf(v1.y - MC) + __expf(v2.y - MC)   \
                 + __expf(v3.y - MC) + __expf(v4.y - MC);                      \
        float ez = __expf(v0.z - MC) + __expf(v1.z - MC) + __expf(v2.z - MC)   \
                 + __expf(v3.z - MC) + __expf(v4.z - MC);                      \
        float ew = __expf(v0.w - MC) + __expf(v1.w - MC) + __expf(v2.w - MC)   \
                 + __expf(v3.w - MC) + __expf(v4.w - MC);                      \
        SC = (ex + ey) + (ez + ew);                                            \
    } while (0)
        LSE_CHUNK(0,  m0, s0);
        LSE_CHUNK(5,  m1, s1);
        LSE_CHUNK(10, m2, s2);
        LSE_CHUNK(15, m3, s3);
#undef LSE_CHUNK
        const float t80 = rowp[80];

        const float M = fmaxf(fmaxf(fmaxf(m0, m1), fmaxf(m2, m3)), t80);
        const float S = s0 * __expf(m0 - M) + s1 * __expf(m1 - M)
                      + s2 * __expf(m2 - M) + s3 * __expf(m3 - M)
                      + __expf(t80 - M);
        const float lse = M + logf(S);

        int ct = 0;
        if (!(ov < 0.5f)) ct = gt_labels[bb * NO + ti];
        const float gv = rowp[ct];
        const float ce = lse - gv;

        const float mm = fmaxf(c.x, c.y);
        const float e0 = expf(c.x - mm), e1 = expf(c.y - mm);
        const float score = e1 / (e0 + e1);
        const bool pos = (ct > 0) && (score > 0.01f);

        float cem_v = ce;
        if (pos) {
            cem_v = 0.0f;
            local_ce += ce;
            const float4 l  = ((const float4*)arm_loc)[row];
            const float4 pr = ((const float4*)priors)[p];
            const float cx = pr.x + l.x * 0.1f * pr.z;
            const float cy = pr.y + l.y * 0.1f * pr.w;
            const float wx = pr.z * expf(l.z * 0.2f);
            const float wy = pr.w * expf(l.w * 0.2f);
            const float dx0 = cx - wx * 0.5f, dy0 = cy - wy * 0.5f;
            const float dx1 = cx + wx * 0.5f, dy1 = cy + wy * 0.5f;
            const float csx = (dx0 + dx1) * 0.5f, csy = (dy0 + dy1) * 0.5f;
            const float csw = dx1 - dx0,          csh = dy1 - dy0;
            const float4 mt = ((const float4*)gt_boxes)[bb * NO + ti];
            const float t0 = ((mt.x + mt.z) * 0.5f - csx) / (0.1f * csw);
            const float t1 = ((mt.y + mt.w) * 0.5f - csy) / (0.1f * csh);
            const float t2 = logf((mt.z - mt.x) / csw) / 0.2f;
            const float t3 = logf((mt.w - mt.y) / csh) / 0.2f;
            const float4 ol = ((const float4*)odm_loc)[row];
            local_l += smooth_l1(ol.x - t0);
            local_l += smooth_l1(ol.y - t1);
            local_l += smooth_l1(ol.z - t2);
            local_l += smooth_l1(ol.w - t3);
            atomicAdd(&npos[bb], 1);
        }
        cem[row] = cem_v;
    }
    // Block reduction of the two loss sums.
    sl[tid] = local_l; sc[tid] = local_ce;
    __syncthreads();
    for (int st = 128; st > 0; st >>= 1) {
        if (tid < st) { sl[tid] += sl[tid + st]; sc[tid] += sc[tid + st]; }
        __syncthreads();
    }
    if (tid == 0) {
        if (sl[0] != 0.0f) atomicAdd(&acc[0], sl[0]);
        if (sc[0] != 0.0f) atomicAdd(&acc[1], sc[0]);
    }
    __threadfence();
    grid.sync();

    // ======================= P4: hard-negative radix select =======================
    // Blocks 0..NB-1 each select for one batch. No early return (cooperative).
    if (bidx < NB) {
        const int b  = bidx;
        const int np = npos[b];
        int k = 3 * np;
        if (k > NP - 1) k = NP - 1;
        if (k > 0) {
            const float4* row4 = (const float4*)(cem + (size_t)b * NP);  // 4080 float4
            const int w = tid >> 6;
            if (tid == 0) { sh_prefix = 0u; sh_mask = 0u; sh_krem = (unsigned)k; }
            __syncthreads();

            for (int pass = 3; pass >= 0; --pass) {
                const unsigned mask   = sh_mask;
                const unsigned prefix = sh_prefix;
                const unsigned krem   = sh_krem;
                const int shift = pass * 8;

                hist[0][tid] = 0u; hist[1][tid] = 0u;
                hist[2][tid] = 0u; hist[3][tid] = 0u;
                __syncthreads();

                for (int i = tid; i < 4080; i += 256) {
                    const float4 v = row4[i];
                    const unsigned u0 = __float_as_uint(v.x);
                    const unsigned u1 = __float_as_uint(v.y);
                    const unsigned u2 = __float_as_uint(v.z);
                    const unsigned u3 = __float_as_uint(v.w);
                    if ((u0 & mask) == prefix) atomicAdd(&hist[w][(u0 >> shift) & 255u], 1u);
                    if ((u1 & mask) == prefix) atomicAdd(&hist[w][(u1 >> shift) & 255u], 1u);
                    if ((u2 & mask) == prefix) atomicAdd(&hist[w][(u2 >> shift) & 255u], 1u);
                    if ((u3 & mask) == prefix) atomicAdd(&hist[w][(u3 >> shift) & 255u], 1u);
                }
                __syncthreads();

                const unsigned h = hist[0][tid] + hist[1][tid] + hist[2][tid] + hist[3][tid];
                scan[tid] = h;
                __syncthreads();
                for (int off = 1; off < 256; off <<= 1) {
                    const unsigned v = (tid + off < 256) ? scan[tid + off] : 0u;
                    __syncthreads();
                    scan[tid] += v;
                    __syncthreads();
                }
                const unsigned sfx = scan[tid];
                if (sfx >= krem && (sfx - h) < krem) {   // unique threshold bin
                    sh_prefix = prefix | ((unsigned)tid << shift);
                    sh_mask   = mask | (255u << shift);
                    sh_krem   = krem - (sfx - h);
                }
                __syncthreads();
            }

            const unsigned T = sh_prefix;   // exact bits of k-th largest
            float    lsum = 0.0f;
            unsigned lcnt = 0;
            for (int i = tid; i < 4080; i += 256) {
                const float4 v = row4[i];
                if (__float_as_uint(v.x) > T) { lsum += v.x; lcnt++; }
                if (__float_as_uint(v.y) > T) { lsum += v.y; lcnt++; }
                if (__float_as_uint(v.z) > T) { lsum += v.z; lcnt++; }
                if (__float_as_uint(v.w) > T) { lsum += v.w; lcnt++; }
            }
            sl[tid] = lsum; scnt[tid] = lcnt;
            __syncthreads();
            for (int st = 128; st > 0; st >>= 1) {
                if (tid < st) { sl[tid] += sl[tid + st]; scnt[tid] += scnt[tid + st]; }
                __syncthreads();
            }
            if (tid == 0) {
                const float tf = __uint_as_float(T);
                atomicAdd(&acc[2], sl[0] + (float)(k - (int)scnt[0]) * tf);
            }
        }
    }
    __threadfence();
    grid.sync();

    // ======================= P5: finalize =======================
    if (bidx == 0 && tid < 64) {
        int n = npos[tid];
        #pragma unroll
        for (int d = 1; d < 64; d <<= 1) n += __shfl_xor(n, d, 64);
        if (tid == 0) {
            const float N = (float)n;
            out[0] = acc[0] / N;
            out[1] = (acc[1] + acc[2]) / N;
        }
    }
}

extern "C" void kernel_launch(void* const* d_in, const int* in_sizes, int n_in,
                              void* d_out, int out_size, void* d_ws, size_t ws_size,
                              hipStream_t stream)
{
    const float* arm_loc   = (const float*)d_in[0];
    const float* arm_conf  = (const float*)d_in[1];
    const float* odm_loc   = (const float*)d_in[2];
    const float* odm_conf  = (const float*)d_in[3];
    const float* priors    = (const float*)d_in[4];
    const float* gt_boxes  = (const float*)d_in[5];
    const int*   gt_labels = (const int*)d_in[6];
    float* out = (float*)d_out;

    char* ws = (char*)d_ws;
    unsigned long long* best_key = (unsigned long long*)ws;          // 12288 B
    int*   npos = (int*)  (ws + 12288);                              // 256 B
    float* acc  = (float*)(ws + 12544);                              // 16 B
    float* bto  = (float*)(ws + 12800);
    int*   bti  = (int*)  (ws + 12800 + (size_t)NB * NP * 4);
    float* cem  = (float*)(ws + 12800 + 2ULL * NB * NP * 4);

    hipMemsetAsync(d_ws, 0, 12560, stream);

    // Cooperative grid: exactly the co-resident capacity (pure host query,
    // graph-capture-safe). 256 CUs on MI355X.
    static int blocks_per_cu = 0;
    if (blocks_per_cu == 0) {
        hipOccupancyMaxActiveBlocksPerMultiprocessor(&blocks_per_cu, k_fused, 256, 0);
        if (blocks_per_cu < 1) blocks_per_cu = 1;
    }
    int grid = blocks_per_cu * 256;
    if (grid > 4080) grid = 4080;

    void* args[] = { (void*)&arm_loc, (void*)&arm_conf, (void*)&odm_loc,
                     (void*)&odm_conf, (void*)&priors, (void*)&gt_boxes,
                     (void*)&gt_labels, (void*)&best_key, (void*)&npos,
                     (void*)&acc, (void*)&bto, (void*)&bti, (void*)&cem,
                     (void*)&out };
    hipLaunchCooperativeKernel((void*)k_fused, dim3(grid), dim3(256),
                               args, 0, stream);
}

// Round 6
// 596.840 us; speedup vs baseline: 2.1050x; 2.1050x over previous
//
#include <hip/hip_runtime.h>
#include <math.h>

#define NB 64
#define NP 16320
#define NO 24
#define NC 81

// ---------------------------------------------------------------------------
// Workspace layout (bytes):
//   [0,           12288)   best_key  : u64[NB*NO]   (zeroed each launch)
//   [12288,       12544)   npos      : int[NB]      (zeroed)
//   [12544,       12560)   acc       : float[4]     (zeroed) 0=loss_l 1=ce_pos 2=ce_neg
//   [12800,       ...  )   bto       : float[NB*NP]
//   next                   bti       : int  [NB*NP]
//   next                   ce_mine   : float[NB*NP]
// ---------------------------------------------------------------------------

__device__ __forceinline__ float smooth_l1(float d) {
    float a = fabsf(d);
    return (a < 1.0f) ? 0.5f * a * a : a - 0.5f;
}

// 4-float group with alignment 4 (odm_conf rows are 324 B -> only 4-B aligned).
struct f4a { float x, y, z, w; };

// Kernel 1: decode ARM boxes, IoU vs truths, per-prior best (bto/bti),
// per-truth best prior. Each thread owns 4 priors (block = 1024 priors);
// per-object cross-lane reduction uses a single packed u64 key
// (iou_bits<<32 | ~p; ties -> smallest p).   [R4 version, unchanged]
__global__ __launch_bounds__(256) void k_match(
    const float* __restrict__ arm_loc, const float* __restrict__ priors,
    const float* __restrict__ gt_boxes,
    float* __restrict__ bto, int* __restrict__ bti,
    unsigned long long* __restrict__ best_key)
{
    const int b     = blockIdx.y;
    const int tid   = threadIdx.x;
    const int pbase = blockIdx.x * 1024;

    __shared__ float tr[NO * 4];
    __shared__ unsigned long long sh_best[NO];
    if (tid < NO * 4) tr[tid] = gt_boxes[b * NO * 4 + tid];
    if (tid < NO)     sh_best[tid] = 0ULL;
    __syncthreads();

    float x0[4], y0[4], x1[4], y1[4], ab[4];
    bool  val[4];
    #pragma unroll
    for (int c = 0; c < 4; ++c) {
        const int p = pbase + c * 256 + tid;
        val[c] = (p < NP);
        const int pc = val[c] ? p : 0;
        const float4 l  = ((const float4*)arm_loc)[(size_t)b * NP + pc];
        const float4 pr = ((const float4*)priors)[pc];
        const float cx = pr.x + l.x * 0.1f * pr.z;
        const float cy = pr.y + l.y * 0.1f * pr.w;
        const float wx = pr.z * expf(l.z * 0.2f);
        const float wy = pr.w * expf(l.w * 0.2f);
        x0[c] = cx - wx * 0.5f; y0[c] = cy - wy * 0.5f;
        x1[c] = cx + wx * 0.5f; y1[c] = cy + wy * 0.5f;
        ab[c] = (x1[c] - x0[c]) * (y1[c] - y0[c]);
    }

    float best[4]  = {-1.0f, -1.0f, -1.0f, -1.0f};
    int   besto[4] = {0, 0, 0, 0};

    for (int o = 0; o < NO; ++o) {
        const float tx0 = tr[o * 4 + 0], ty0 = tr[o * 4 + 1];
        const float tx1 = tr[o * 4 + 2], ty1 = tr[o * 4 + 3];
        const float aa  = (tx1 - tx0) * (ty1 - ty0);

        unsigned long long key = 0ULL;
        #pragma unroll
        for (int c = 0; c < 4; ++c) {
            const float iw = fmaxf(fminf(tx1, x1[c]) - fmaxf(tx0, x0[c]), 0.0f);
            const float ih = fmaxf(fminf(ty1, y1[c]) - fmaxf(ty0, y0[c]), 0.0f);
            const float inter = iw * ih;
            const float iou = inter / (aa + ab[c] - inter);
            if (iou > best[c]) { best[c] = iou; besto[c] = o; }  // first occurrence
            const int p = pbase + c * 256 + tid;
            const unsigned long long kc =
                ((unsigned long long)__float_as_uint(iou) << 32) | (unsigned)~(unsigned)p;
            if (val[c] && kc > key) key = kc;
        }
        #pragma unroll
        for (int d = 1; d < 64; d <<= 1) {
            const unsigned long long k2 = __shfl_xor(key, d, 64);
            if (k2 > key) key = k2;
        }
        if ((tid & 63) == 0) atomicMax(&sh_best[o], key);
    }

    #pragma unroll
    for (int c = 0; c < 4; ++c) {
        if (val[c]) {
            const size_t idx = (size_t)b * NP + (pbase + c * 256 + tid);
            bto[idx] = best[c];
            bti[idx] = besto[c];
        }
    }
    __syncthreads();
    if (tid < NO) atomicMax(&best_key[b * NO + tid], sh_best[tid]);
}

// Kernel 2: force-match best prior per truth (last write wins = np scatter).
__global__ void k_force(const unsigned long long* __restrict__ best_key,
                        float* __restrict__ bto, int* __restrict__ bti)
{
    const int b = blockIdx.x * blockDim.x + threadIdx.x;
    if (b >= NB) return;
    for (int o = 0; o < NO; ++o) {
        const unsigned long long k = best_key[b * NO + o];
        const unsigned p = ~(unsigned)(k & 0xffffffffULL);
        bto[(size_t)b * NP + p] = 2.0f;
        bti[(size_t)b * NP + p] = o;
    }
}

// Kernel 3 v6: max memory-level parallelism. Five rounds showed dur invariant
// (~450us) across four structures with all pipes <6% busy; outstanding bytes
// per CU computed from delivered BW (~0.77 B/cy) x latency was <1KB -- the
// kernel never had more than ~5 lines in flight because every variant
// consumed loads in small dependent clumps (VGPR 36-56). Fix: launch_bounds
// (256,3) -> VGPR cap ~168; issue ALL 21 row loads into 84 named payload
// VGPRs before ANY consumption. 21 outstanding vmem/wave x ~12 waves/CU.
// R1's version of this idea died to the allocator choosing 36 VGPR + spill;
// the explicit min-waves arg is the difference.
__global__ __launch_bounds__(256, 3) void k_loss(
    const float* __restrict__ arm_loc, const float* __restrict__ arm_conf,
    const float* __restrict__ odm_loc, const float* __restrict__ odm_conf,
    const float* __restrict__ priors,  const float* __restrict__ gt_boxes,
    const int*   __restrict__ gt_labels,
    const float* __restrict__ bto, const int* __restrict__ bti,
    float* __restrict__ ce_mine, int* __restrict__ npos, float* __restrict__ acc)
{
    const int tid = threadIdx.x;
    const size_t row = (size_t)blockIdx.x * 256 + tid;
    const int bb = (int)(row / NP);
    const int p  = (int)(row - (size_t)bb * NP);

    // Small front loads.
    const float  ov = bto[row];
    const int    ti = bti[row];
    const float2 c  = ((const float2*)arm_conf)[row];

    const float* rowp = odm_conf + row * (size_t)NC;
    const f4a*   rp4  = (const f4a*)rowp;

    // Issue ALL 21 row loads back-to-back (84 payload VGPRs in flight).
    const f4a v00 = rp4[0],  v01 = rp4[1],  v02 = rp4[2],  v03 = rp4[3];
    const f4a v04 = rp4[4],  v05 = rp4[5],  v06 = rp4[6],  v07 = rp4[7];
    const f4a v08 = rp4[8],  v09 = rp4[9],  v10 = rp4[10], v11 = rp4[11];
    const f4a v12 = rp4[12], v13 = rp4[13], v14 = rp4[14], v15 = rp4[15];
    const f4a v16 = rp4[16], v17 = rp4[17], v18 = rp4[18], v19 = rp4[19];
    const float t80 = rowp[80];

#define FM4(v) fmaxf(fmaxf((v).x, (v).y), fmaxf((v).z, (v).w))
    float ma = FM4(v00), mb = FM4(v01), mc = FM4(v02), md = FM4(v03);
    ma = fmaxf(ma, FM4(v04)); mb = fmaxf(mb, FM4(v05));
    mc = fmaxf(mc, FM4(v06)); md = fmaxf(md, FM4(v07));
    ma = fmaxf(ma, FM4(v08)); mb = fmaxf(mb, FM4(v09));
    mc = fmaxf(mc, FM4(v10)); md = fmaxf(md, FM4(v11));
    ma = fmaxf(ma, FM4(v12)); mb = fmaxf(mb, FM4(v13));
    mc = fmaxf(mc, FM4(v14)); md = fmaxf(md, FM4(v15));
    ma = fmaxf(ma, FM4(v16)); mb = fmaxf(mb, FM4(v17));
    mc = fmaxf(mc, FM4(v18)); md = fmaxf(md, FM4(v19));
    const float m = fmaxf(fmaxf(fmaxf(ma, mb), fmaxf(mc, md)), t80);
#undef FM4

#define ES4(v, a) a += __expf((v).x - m) + __expf((v).y - m) \
                     + __expf((v).z - m) + __expf((v).w - m)
    float a0 = 0.0f, a1 = 0.0f, a2 = 0.0f, a3 = 0.0f;
    ES4(v00, a0); ES4(v01, a1); ES4(v02, a2); ES4(v03, a3);
    ES4(v04, a0); ES4(v05, a1); ES4(v06, a2); ES4(v07, a3);
    ES4(v08, a0); ES4(v09, a1); ES4(v10, a2); ES4(v11, a3);
    ES4(v12, a0); ES4(v13, a1); ES4(v14, a2); ES4(v15, a3);
    ES4(v16, a0); ES4(v17, a1); ES4(v18, a2); ES4(v19, a3);
#undef ES4
    const float S = (a0 + a1) + (a2 + a3) + __expf(t80 - m);
    const float lse = m + logf(S);

    // Target class + gather (row line is cache-hot after the stream above).
    int ct = 0;
    if (!(ov < 0.5f)) ct = gt_labels[bb * NO + ti];
    const float gv = rowp[ct];
    const float ce = lse - gv;

    // ARM objectness filter (ocml expf on the threshold path).
    const float mm = fmaxf(c.x, c.y);
    const float e0 = expf(c.x - mm), e1 = expf(c.y - mm);
    const float score = e1 / (e0 + e1);
    const bool pos = (ct > 0) && (score > 0.01f);

    float local_l = 0.0f, local_ce = 0.0f;
    float cem = ce;
    if (pos) {
        cem      = 0.0f;
        local_ce = ce;
        const float4 l  = ((const float4*)arm_loc)[row];
        const float4 pr = ((const float4*)priors)[p];
        const float cx = pr.x + l.x * 0.1f * pr.z;
        const float cy = pr.y + l.y * 0.1f * pr.w;
        const float wx = pr.z * expf(l.z * 0.2f);
        const float wy = pr.w * expf(l.w * 0.2f);
        const float dx0 = cx - wx * 0.5f, dy0 = cy - wy * 0.5f;
        const float dx1 = cx + wx * 0.5f, dy1 = cy + wy * 0.5f;
        const float csx = (dx0 + dx1) * 0.5f, csy = (dy0 + dy1) * 0.5f;
        const float csw = dx1 - dx0,          csh = dy1 - dy0;
        const float4 mt = ((const float4*)gt_boxes)[bb * NO + ti];
        const float t0 = ((mt.x + mt.z) * 0.5f - csx) / (0.1f * csw);
        const float t1 = ((mt.y + mt.w) * 0.5f - csy) / (0.1f * csh);
        const float t2 = logf((mt.z - mt.x) / csw) / 0.2f;
        const float t3 = logf((mt.w - mt.y) / csh) / 0.2f;
        const float4 ol = ((const float4*)odm_loc)[row];
        local_l += smooth_l1(ol.x - t0);
        local_l += smooth_l1(ol.y - t1);
        local_l += smooth_l1(ol.z - t2);
        local_l += smooth_l1(ol.w - t3);
    }
    ce_mine[row] = cem;

    // Per-batch positive count: one atomic per wave (waves never straddle a
    // batch: NP % 64 == 0), 64x fewer atomics than per-thread.
    const unsigned long long bal = __ballot(pos);
    if ((tid & 63) == 0 && bal) atomicAdd(&npos[bb], __popcll(bal));

    // Block reduction for the two loss sums.
    __shared__ float sl[256];
    __shared__ float sc[256];
    sl[tid] = local_l; sc[tid] = local_ce;
    __syncthreads();
    for (int st = 128; st > 0; st >>= 1) {
        if (tid < st) {
            sl[tid] += sl[tid + st];
            sc[tid] += sc[tid + st];
        }
        __syncthreads();
    }
    if (tid == 0) {
        if (sl[0] != 0.0f) atomicAdd(&acc[0], sl[0]);
        if (sc[0] != 0.0f) atomicAdd(&acc[1], sc[0]);
    }
}

// Kernel 4: per-row radix select of k-th largest ce_mine.  [R4 version]
__global__ __launch_bounds__(256) void k_select(
    const float* __restrict__ ce_mine, const int* __restrict__ npos,
    float* __restrict__ acc)
{
    const int b   = blockIdx.x;
    const int tid = threadIdx.x;
    const int np  = npos[b];
    int k = 3 * np;
    if (k > NP - 1) k = NP - 1;
    if (k <= 0) return;

    const float4* row4 = (const float4*)(ce_mine + (size_t)b * NP);  // 4080 float4
    const int w = tid >> 6;

    __shared__ unsigned int hist[4][257];
    __shared__ unsigned int scan[256];
    __shared__ unsigned int sh_prefix, sh_mask, sh_krem;
    if (tid == 0) { sh_prefix = 0u; sh_mask = 0u; sh_krem = (unsigned)k; }
    __syncthreads();

    for (int pass = 3; pass >= 0; --pass) {
        const unsigned mask   = sh_mask;
        const unsigned prefix = sh_prefix;
        const unsigned krem   = sh_krem;
        const int shift = pass * 8;

        hist[0][tid] = 0u; hist[1][tid] = 0u; hist[2][tid] = 0u; hist[3][tid] = 0u;
        __syncthreads();

        for (int i = tid; i < 4080; i += 256) {
            const float4 v = row4[i];
            const unsigned u0 = __float_as_uint(v.x);
            const unsigned u1 = __float_as_uint(v.y);
            const unsigned u2 = __float_as_uint(v.z);
            const unsigned u3 = __float_as_uint(v.w);
            if ((u0 & mask) == prefix) atomicAdd(&hist[w][(u0 >> shift) & 255u], 1u);
            if ((u1 & mask) == prefix) atomicAdd(&hist[w][(u1 >> shift) & 255u], 1u);
            if ((u2 & mask) == prefix) atomicAdd(&hist[w][(u2 >> shift) & 255u], 1u);
            if ((u3 & mask) == prefix) atomicAdd(&hist[w][(u3 >> shift) & 255u], 1u);
        }
        __syncthreads();

        const unsigned h = hist[0][tid] + hist[1][tid] + hist[2][tid] + hist[3][tid];
        scan[tid] = h;
        __syncthreads();
        for (int off = 1; off < 256; off <<= 1) {
            const unsigned v = (tid + off < 256) ? scan[tid + off] : 0u;
            __syncthreads();
            scan[tid] += v;
            __syncthreads();
        }
        const unsigned sfx = scan[tid];
        if (sfx >= krem && (sfx - h) < krem) {
            sh_prefix = prefix | ((unsigned)tid << shift);
            sh_mask   = mask | (255u << shift);
            sh_krem   = krem - (sfx - h);
        }
        __syncthreads();
    }

    const unsigned T = sh_prefix;
    float    lsum = 0.0f;
    unsigned lcnt = 0;
    for (int i = tid; i < 4080; i += 256) {
        const float4 v = row4[i];
        if (__float_as_uint(v.x) > T) { lsum += v.x; lcnt++; }
        if (__float_as_uint(v.y) > T) { lsum += v.y; lcnt++; }
        if (__float_as_uint(v.z) > T) { lsum += v.z; lcnt++; }
        if (__float_as_uint(v.w) > T) { lsum += v.w; lcnt++; }
    }
    __shared__ float    ssum[256];
    __shared__ unsigned scnt[256];
    ssum[tid] = lsum; scnt[tid] = lcnt;
    __syncthreads();
    for (int st = 128; st > 0; st >>= 1) {
        if (tid < st) { ssum[tid] += ssum[tid + st]; scnt[tid] += scnt[tid + st]; }
        __syncthreads();
    }
    if (tid == 0) {
        const float tf = __uint_as_float(T);
        const float contrib = ssum[0] + (float)(k - (int)scnt[0]) * tf;
        atomicAdd(&acc[2], contrib);
    }
}

// Kernel 5: finalize (one wave = 64 threads, shuffle-reduced npos sum).
__global__ void k_final(const float* __restrict__ acc, const int* __restrict__ npos,
                        float* __restrict__ out)
{
    const int tid = threadIdx.x;          // launched with 64 threads
    int n = npos[tid];
    #pragma unroll
    for (int d = 1; d < 64; d <<= 1) n += __shfl_xor(n, d, 64);
    if (tid == 0) {
        const float N = (float)n;
        out[0] = acc[0] / N;
        out[1] = (acc[1] + acc[2]) / N;
    }
}

extern "C" void kernel_launch(void* const* d_in, const int* in_sizes, int n_in,
                              void* d_out, int out_size, void* d_ws, size_t ws_size,
                              hipStream_t stream)
{
    const float* arm_loc   = (const float*)d_in[0];
    const float* arm_conf  = (const float*)d_in[1];
    const float* odm_loc   = (const float*)d_in[2];
    const float* odm_conf  = (const float*)d_in[3];
    const float* priors    = (const float*)d_in[4];
    const float* gt_boxes  = (const float*)d_in[5];
    const int*   gt_labels = (const int*)d_in[6];
    float* out = (float*)d_out;

    char* ws = (char*)d_ws;
    unsigned long long* best_key = (unsigned long long*)ws;          // 12288 B
    int*   npos = (int*)  (ws + 12288);                              // 256 B
    float* acc  = (float*)(ws + 12544);                              // 16 B
    float* bto  = (float*)(ws + 12800);
    int*   bti  = (int*)  (ws + 12800 + (size_t)NB * NP * 4);
    float* cem  = (float*)(ws + 12800 + 2ULL * NB * NP * 4);

    hipMemsetAsync(d_ws, 0, 12560, stream);

    dim3 gm((NP + 1023) / 1024, NB);
    k_match <<<gm, 256, 0, stream>>>(arm_loc, priors, gt_boxes, bto, bti, best_key);
    k_force <<<1, 64, 0, stream>>>(best_key, bto, bti);
    k_loss  <<<4080, 256, 0, stream>>>(arm_loc, arm_conf, odm_loc, odm_conf, priors,
                                       gt_boxes, gt_labels, bto, bti, cem, npos, acc);
    k_select<<<NB, 256, 0, stream>>>(cem, npos, acc);
    k_final <<<1, 64, 0, stream>>>(acc, npos, out);
}